// Round 12
// baseline (196.078 us; speedup 1.0000x reference)
//
#include <hip/hip_runtime.h>
#include <stdint.h>

// R12 = R10's exact pipeline, with k_hist_lds launched TWICE (idempotent) as a
// timing probe: dur_us - 141.7 = true hist kernel time. No other changes.

static constexpr uint32_t SEQN = 4194304u;
static constexpr uint32_t BINS = 65536u;
static constexpr uint32_t QWORDS = BINS / 4u;       // u8x4-packed words
static constexpr uint32_t NBLK = 512u;              // 2 per CU (64 KiB LDS each)
static constexpr uint32_t NTHR = 1024u;
static constexpr uint32_t ROWS_PER_BLK = SEQN / NBLK;  // 8192 (u8-safe)

// ---------- LDS-privatized histogram: batch-8 loads + DPP key assembly ----------
__global__ __launch_bounds__(NTHR) void k_hist_lds(const float4* __restrict__ in4,
                                                   uint32_t* __restrict__ partial) {
  __shared__ __align__(16) uint32_t h[QWORDS];  // 64 KiB u8x4 counters
  uint32_t tid = threadIdx.x, blk = blockIdx.x;
  uint4* hv = (uint4*)h;
  for (uint32_t i = tid; i < QWORDS / 4u; i += NTHR) hv[i] = make_uint4(0u, 0u, 0u, 0u);
  __syncthreads();
  uint32_t q = tid & 3u;
  uint32_t shift = 12u - (q << 2);        // quad q covers bits [4q,4q+4) MSB-first
  bool leader = (q == 0u);
  const float4* base = in4 + (size_t)blk * (ROWS_PER_BLK * 4u);
#pragma unroll
  for (uint32_t b = 0; b < 4u; ++b) {
    float4 v[8];
#pragma unroll
    for (uint32_t u = 0; u < 8u; ++u)       // 8 independent coalesced 16B loads
      v[u] = base[(size_t)(b * 8u + u) * NTHR + tid];
#pragma unroll
    for (uint32_t u = 0; u < 8u; ++u) {
      float nf = ((v[u].x * 2.0f + v[u].y) * 2.0f + v[u].z) * 2.0f + v[u].w;
      uint32_t part = ((uint32_t)nf) << shift;
      uint32_t s1 = part + (uint32_t)__builtin_amdgcn_mov_dpp((int)part, 0xB1, 0xF, 0xF, true);
      uint32_t key = s1 + (uint32_t)__builtin_amdgcn_mov_dpp((int)s1, 0x4E, 0xF, 0xF, true);
      if (leader) atomicAdd(&h[key >> 2], 1u << ((key & 3u) << 3));
    }
  }
  __syncthreads();
  uint4* dst = (uint4*)(partial + (size_t)blk * QWORDS);
  for (uint32_t i = tid; i < QWORDS / 4u; i += NTHR) dst[i] = hv[i];
}

// ---------- fused reduce (512-fan-in) + hist + per-1024-bin totals ----------
__global__ __launch_bounds__(NTHR) void k_reduceB(const uint32_t* __restrict__ partial,
                                                  uint32_t* __restrict__ hist,
                                                  uint32_t* __restrict__ blkTot) {
  __shared__ uint2 acc[4][256];
  __shared__ uint32_t wt[4];
  uint32_t tid = threadIdx.x, blk = blockIdx.x;
  uint32_t wl = tid & 255u, g = tid >> 8;
  uint32_t w = blk * 256u + wl;
  uint32_t e = 0u, o = 0u;
  uint32_t p0 = g * (NBLK / 4u);
#pragma unroll 8
  for (uint32_t p = p0; p < p0 + NBLK / 4u; ++p) {
    uint32_t v = partial[(size_t)p * QWORDS + w];
    e += v & 0x00FF00FFu;
    o += (v >> 8) & 0x00FF00FFu;
  }
  acc[g][wl] = make_uint2(e, o);
  __syncthreads();
  if (g == 0u) {
    uint2 a1 = acc[1][wl], a2 = acc[2][wl], a3 = acc[3][wl];
    e += a1.x + a2.x + a3.x;
    o += a1.y + a2.y + a3.y;
    uint32_t c0 = e & 0xFFFFu, c2 = e >> 16, c1 = o & 0xFFFFu, c3 = o >> 16;
    ((uint4*)hist)[w] = make_uint4(c0, c1, c2, c3);
    uint32_t ssum = c0 + c1 + c2 + c3;
    for (int d = 1; d < 64; d <<= 1) ssum += __shfl_xor(ssum, d, 64);
    if ((tid & 63u) == 0u) wt[tid >> 6] = ssum;
  }
  __syncthreads();
  if (tid == 0u) blkTot[blk] = wt[0] + wt[1] + wt[2] + wt[3];
}

// ---------- fallback global-atomic histogram (small ws) ----------
__global__ __launch_bounds__(256) void k_zero(uint32_t* __restrict__ hist) {
  uint32_t i = blockIdx.x * 256u + threadIdx.x;
  if (i < BINS) hist[i] = 0u;
}

__global__ __launch_bounds__(256) void k_hist(const float4* __restrict__ in4,
                                              uint32_t* __restrict__ hist) {
  uint32_t r = blockIdx.x * 256u + threadIdx.x;
  if (r >= SEQN) return;
  uint32_t key = 0u;
#pragma unroll
  for (uint32_t qq = 0; qq < 4u; ++qq) {
    float4 v = in4[(size_t)r * 4u + qq];
    uint32_t nib = ((uint32_t)v.x << 3) | ((uint32_t)v.y << 2) |
                   ((uint32_t)v.z << 1) | (uint32_t)v.w;
    key = (key << 4) | nib;
  }
  atomicAdd(&hist[key], 1u);
}

__global__ __launch_bounds__(256) void k_scan1(const uint32_t* __restrict__ hist,
                                               uint32_t* __restrict__ blkTot) {
  uint32_t tid = threadIdx.x, blk = blockIdx.x;
  uint32_t b0 = blk * 1024u + tid * 4u;
  uint32_t s = hist[b0] + hist[b0 + 1] + hist[b0 + 2] + hist[b0 + 3];
  for (int d = 1; d < 64; d <<= 1) s += __shfl_xor(s, d, 64);
  __shared__ uint32_t wt[4];
  if ((tid & 63u) == 0u) wt[tid >> 6] = s;
  __syncthreads();
  if (tid == 0u) blkTot[blk] = wt[0] + wt[1] + wt[2] + wt[3];
}

// ---------- fused scan: block base from blkTot, then per-bin offsets ----------
__global__ __launch_bounds__(256) void k_scanB(const uint32_t* __restrict__ hist,
                                               const uint32_t* __restrict__ blkTot,
                                               uint32_t* __restrict__ offs) {
  __shared__ uint32_t s_base;
  __shared__ uint32_t wt[4];
  uint32_t tid = threadIdx.x, blk = blockIdx.x;
  if (tid < 64u) {
    uint32_t v = blkTot[tid];
    uint32_t incl = v;
    for (int d = 1; d < 64; d <<= 1) {
      uint32_t n = __shfl_up(incl, d, 64);
      if (tid >= (uint32_t)d) incl += n;
    }
    if (tid == blk) s_base = incl - v;
  }
  __syncthreads();
  uint32_t lane = tid & 63u, wid = tid >> 6;
  uint32_t b0 = blk * 1024u + tid * 4u;
  uint4 c = ((const uint4*)hist)[b0 >> 2];
  uint32_t s = c.x + c.y + c.z + c.w;
  uint32_t incl = s;
  for (int d = 1; d < 64; d <<= 1) {
    uint32_t n = __shfl_up(incl, d, 64);
    if (lane >= (uint32_t)d) incl += n;
  }
  if (lane == 63u) wt[wid] = incl;
  __syncthreads();
  uint32_t wbase = 0u;
  for (uint32_t w = 0; w < wid; ++w) wbase += wt[w];
  uint32_t base = s_base + wbase + (incl - s);
  ((uint4*)offs)[b0 >> 2] = make_uint4(base, base + c.x, base + c.x + c.y,
                                       base + c.x + c.y + c.z);
}

// ---------- writer: wave-autonomous, 8 keys/wave ----------
__global__ __launch_bounds__(256) void k_write(const uint32_t* __restrict__ hist,
                                               const uint32_t* __restrict__ offs,
                                               float4* __restrict__ out4) {
  __shared__ uint32_t s_off[32], s_cnt[32];
  uint32_t tid = threadIdx.x, blk = blockIdx.x;
  if (tid < 32u) {
    uint32_t k = blk * 32u + tid;
    s_off[tid] = offs[k];
    s_cnt[tid] = hist[k];
  }
  __syncthreads();
  uint32_t lane = tid & 63u, wid = tid >> 6;
  uint32_t q = lane & 3u;
  for (uint32_t kk = 0; kk < 8u; ++kk) {
    uint32_t ki = wid * 8u + kk;
    uint32_t k = blk * 32u + ki;
    uint32_t off = s_off[ki], cnt = s_cnt[ki];
    float4 pat;
    pat.x = (float)((k >> (15u - (q * 4u + 0u))) & 1u);
    pat.y = (float)((k >> (15u - (q * 4u + 1u))) & 1u);
    pat.z = (float)((k >> (15u - (q * 4u + 2u))) & 1u);
    pat.w = (float)((k >> (15u - (q * 4u + 3u))) & 1u);
    size_t base = (size_t)off * 4u;
    uint32_t tot = cnt * 4u;
    for (uint32_t j = lane; j < tot; j += 64u) out4[base + j] = pat;
  }
}

extern "C" void kernel_launch(void* const* d_in, const int* in_sizes, int n_in,
                              void* d_out, int out_size, void* d_ws, size_t ws_size,
                              hipStream_t stream) {
  const float4* in4 = (const float4*)d_in[0];
  float4* out4 = (float4*)d_out;
  uint32_t* hist = (uint32_t*)d_ws;               // 65536 u32
  uint32_t* offs = hist + BINS;                   // 65536 u32
  uint32_t* blkTot = offs + BINS;                 // 64 u32 (pad to 1024)
  uint32_t* partial = blkTot + 1024u;             // NBLK * QWORDS u32 = 32 MiB

  size_t need = ((size_t)2 * BINS + 1024u + (size_t)NBLK * QWORDS) * 4u;
  if (ws_size >= need) {
    // TIMING PROBE: launched twice (idempotent). dur_us delta vs 141.7 = hist time.
    k_hist_lds<<<NBLK, NTHR, 0, stream>>>(in4, partial);
    k_hist_lds<<<NBLK, NTHR, 0, stream>>>(in4, partial);
    k_reduceB<<<64, NTHR, 0, stream>>>(partial, hist, blkTot);
  } else {
    k_zero<<<BINS / 256, 256, 0, stream>>>(hist);
    k_hist<<<SEQN / 256, 256, 0, stream>>>(in4, hist);
    k_scan1<<<64, 256, 0, stream>>>(hist, blkTot);
  }
  k_scanB<<<64, 256, 0, stream>>>(hist, blkTot, offs);
  k_write<<<BINS / 32, 256, 0, stream>>>(hist, offs, out4);
}

// Round 13
// 134.154 us; speedup vs baseline: 1.4616x; 1.4616x over previous
//
#include <hip/hip_runtime.h>
#include <stdint.h>

static constexpr uint32_t SEQN = 4194304u;
static constexpr uint32_t BINS = 65536u;
static constexpr uint32_t QWORDS = BINS / 4u;       // u8x4-packed words (16384)
static constexpr uint32_t NBLK = 256u;              // 1 block/CU, 16 waves
static constexpr uint32_t NTHR = 1024u;
static constexpr uint32_t ROWS_PER_BLK = SEQN / NBLK;  // 16384 (u8-safe: lambda=0.25)

// ---------- LDS-privatized histogram: batch-8 loads + DPP key assembly ----------
__global__ __launch_bounds__(NTHR) void k_hist_lds(const float4* __restrict__ in4,
                                                   uint32_t* __restrict__ partial,
                                                   uint32_t* __restrict__ blkTot) {
  __shared__ __align__(16) uint32_t h[QWORDS];  // 64 KiB u8x4 counters
  uint32_t tid = threadIdx.x, blk = blockIdx.x;
  if (blk == 0u && tid < 64u) blkTot[tid] = 0u;   // for reduce's atomics (runs before)
  uint4* hv = (uint4*)h;
  for (uint32_t i = tid; i < QWORDS / 4u; i += NTHR) hv[i] = make_uint4(0u, 0u, 0u, 0u);
  __syncthreads();
  uint32_t q = tid & 3u;
  uint32_t shift = 12u - (q << 2);        // quad q covers bits [4q,4q+4) MSB-first
  bool leader = (q == 0u);
  const float4* base = in4 + (size_t)blk * (ROWS_PER_BLK * 4u);
#pragma unroll
  for (uint32_t b = 0; b < 8u; ++b) {
    float4 v[8];
#pragma unroll
    for (uint32_t u = 0; u < 8u; ++u)       // 8 independent coalesced 16B loads
      v[u] = base[(size_t)(b * 8u + u) * NTHR + tid];
#pragma unroll
    for (uint32_t u = 0; u < 8u; ++u) {
      float nf = ((v[u].x * 2.0f + v[u].y) * 2.0f + v[u].z) * 2.0f + v[u].w;
      uint32_t part = ((uint32_t)nf) << shift;
      uint32_t s1 = part + (uint32_t)__builtin_amdgcn_mov_dpp((int)part, 0xB1, 0xF, 0xF, true);
      uint32_t key = s1 + (uint32_t)__builtin_amdgcn_mov_dpp((int)s1, 0x4E, 0xF, 0xF, true);
      if (leader) atomicAdd(&h[key >> 2], 1u << ((key & 3u) << 3));
    }
  }
  __syncthreads();
  uint4* dst = (uint4*)(partial + (size_t)blk * QWORDS);
  for (uint32_t i = tid; i < QWORDS / 4u; i += NTHR) dst[i] = hv[i];
}

// ---------- reduce: 256 blocks x 256 thr; block b owns words [b*64,+64) ----------
__global__ __launch_bounds__(256) void k_reduceD(const uint32_t* __restrict__ partial,
                                                 uint32_t* __restrict__ hist,
                                                 uint32_t* __restrict__ blkTot) {
  __shared__ uint2 acc[4][64];
  uint32_t tid = threadIdx.x, b = blockIdx.x;
  uint32_t wl = tid & 63u, g = tid >> 6;   // word-local, partial-group
  uint32_t w = b * 64u + wl;
  uint32_t e = 0u, o = 0u;  // packed u16 pairs (4w,4w+2)/(4w+1,4w+3); 256*255 < 65536
  uint32_t p0 = g * 64u;
#pragma unroll 8
  for (uint32_t p = p0; p < p0 + 64u; ++p) {
    uint32_t v = partial[(size_t)p * QWORDS + w];
    e += v & 0x00FF00FFu;
    o += (v >> 8) & 0x00FF00FFu;
  }
  acc[g][wl] = make_uint2(e, o);
  __syncthreads();
  if (g == 0u) {
    uint2 a1 = acc[1][wl], a2 = acc[2][wl], a3 = acc[3][wl];
    e += a1.x + a2.x + a3.x;
    o += a1.y + a2.y + a3.y;
    uint32_t c0 = e & 0xFFFFu, c2 = e >> 16, c1 = o & 0xFFFFu, c3 = o >> 16;
    ((uint4*)hist)[w] = make_uint4(c0, c1, c2, c3);
    uint32_t ssum = c0 + c1 + c2 + c3;
    for (int d = 1; d < 64; d <<= 1) ssum += __shfl_xor(ssum, d, 64);
    if (wl == 0u) atomicAdd(&blkTot[b >> 2], ssum);  // 4 blocks per 1024-bin entry
  }
}

// ---------- fallback global-atomic histogram (small ws) ----------
__global__ __launch_bounds__(256) void k_zero(uint32_t* __restrict__ hist,
                                              uint32_t* __restrict__ blkTot) {
  uint32_t i = blockIdx.x * 256u + threadIdx.x;
  if (i < BINS) hist[i] = 0u;
  if (i < 64u) blkTot[i] = 0u;
}

__global__ __launch_bounds__(256) void k_hist(const float4* __restrict__ in4,
                                              uint32_t* __restrict__ hist) {
  uint32_t r = blockIdx.x * 256u + threadIdx.x;
  if (r >= SEQN) return;
  uint32_t key = 0u;
#pragma unroll
  for (uint32_t qq = 0; qq < 4u; ++qq) {
    float4 v = in4[(size_t)r * 4u + qq];
    uint32_t nib = ((uint32_t)v.x << 3) | ((uint32_t)v.y << 2) |
                   ((uint32_t)v.z << 1) | (uint32_t)v.w;
    key = (key << 4) | nib;
  }
  atomicAdd(&hist[key], 1u);
}

__global__ __launch_bounds__(256) void k_scan1(const uint32_t* __restrict__ hist,
                                               uint32_t* __restrict__ blkTot) {
  uint32_t tid = threadIdx.x, blk = blockIdx.x;
  uint32_t b0 = blk * 1024u + tid * 4u;
  uint32_t s = hist[b0] + hist[b0 + 1] + hist[b0 + 2] + hist[b0 + 3];
  for (int d = 1; d < 64; d <<= 1) s += __shfl_xor(s, d, 64);
  __shared__ uint32_t wt[4];
  if ((tid & 63u) == 0u) wt[tid >> 6] = s;
  __syncthreads();
  if (tid == 0u) blkTot[blk] = wt[0] + wt[1] + wt[2] + wt[3];
}

// ---------- fused scan: block base from blkTot, then per-bin offsets ----------
__global__ __launch_bounds__(256) void k_scanB(const uint32_t* __restrict__ hist,
                                               const uint32_t* __restrict__ blkTot,
                                               uint32_t* __restrict__ offs) {
  __shared__ uint32_t s_base;
  __shared__ uint32_t wt[4];
  uint32_t tid = threadIdx.x, blk = blockIdx.x;
  if (tid < 64u) {
    uint32_t v = blkTot[tid];
    uint32_t incl = v;
    for (int d = 1; d < 64; d <<= 1) {
      uint32_t n = __shfl_up(incl, d, 64);
      if (tid >= (uint32_t)d) incl += n;
    }
    if (tid == blk) s_base = incl - v;
  }
  __syncthreads();
  uint32_t lane = tid & 63u, wid = tid >> 6;
  uint32_t b0 = blk * 1024u + tid * 4u;
  uint4 c = ((const uint4*)hist)[b0 >> 2];
  uint32_t s = c.x + c.y + c.z + c.w;
  uint32_t incl = s;
  for (int d = 1; d < 64; d <<= 1) {
    uint32_t n = __shfl_up(incl, d, 64);
    if (lane >= (uint32_t)d) incl += n;
  }
  if (lane == 63u) wt[wid] = incl;
  __syncthreads();
  uint32_t wbase = 0u;
  for (uint32_t w = 0; w < wid; ++w) wbase += wt[w];
  uint32_t base = s_base + wbase + (incl - s);
  ((uint4*)offs)[b0 >> 2] = make_uint4(base, base + c.x, base + c.x + c.y,
                                       base + c.x + c.y + c.z);
}

// ---------- writer: wave-autonomous, 8 keys/wave ----------
__global__ __launch_bounds__(256) void k_write(const uint32_t* __restrict__ hist,
                                               const uint32_t* __restrict__ offs,
                                               float4* __restrict__ out4) {
  __shared__ uint32_t s_off[32], s_cnt[32];
  uint32_t tid = threadIdx.x, blk = blockIdx.x;
  if (tid < 32u) {
    uint32_t k = blk * 32u + tid;
    s_off[tid] = offs[k];
    s_cnt[tid] = hist[k];
  }
  __syncthreads();
  uint32_t lane = tid & 63u, wid = tid >> 6;
  uint32_t q = lane & 3u;
  for (uint32_t kk = 0; kk < 8u; ++kk) {
    uint32_t ki = wid * 8u + kk;
    uint32_t k = blk * 32u + ki;
    uint32_t off = s_off[ki], cnt = s_cnt[ki];
    float4 pat;
    pat.x = (float)((k >> (15u - (q * 4u + 0u))) & 1u);
    pat.y = (float)((k >> (15u - (q * 4u + 1u))) & 1u);
    pat.z = (float)((k >> (15u - (q * 4u + 2u))) & 1u);
    pat.w = (float)((k >> (15u - (q * 4u + 3u))) & 1u);
    size_t base = (size_t)off * 4u;
    uint32_t tot = cnt * 4u;
    for (uint32_t j = lane; j < tot; j += 64u) out4[base + j] = pat;
  }
}

extern "C" void kernel_launch(void* const* d_in, const int* in_sizes, int n_in,
                              void* d_out, int out_size, void* d_ws, size_t ws_size,
                              hipStream_t stream) {
  const float4* in4 = (const float4*)d_in[0];
  float4* out4 = (float4*)d_out;
  uint32_t* hist = (uint32_t*)d_ws;               // 65536 u32
  uint32_t* offs = hist + BINS;                   // 65536 u32
  uint32_t* blkTot = offs + BINS;                 // 64 u32 (pad to 1024)
  uint32_t* partial = blkTot + 1024u;             // NBLK * QWORDS u32 = 16 MiB

  size_t need = ((size_t)2 * BINS + 1024u + (size_t)NBLK * QWORDS) * 4u;
  if (ws_size >= need) {
    k_hist_lds<<<NBLK, NTHR, 0, stream>>>(in4, partial, blkTot);
    k_reduceD<<<256, 256, 0, stream>>>(partial, hist, blkTot);
  } else {
    k_zero<<<BINS / 256, 256, 0, stream>>>(hist, blkTot);
    k_hist<<<SEQN / 256, 256, 0, stream>>>(in4, hist);
    k_scan1<<<64, 256, 0, stream>>>(hist, blkTot);
  }
  k_scanB<<<64, 256, 0, stream>>>(hist, blkTot, offs);
  k_write<<<BINS / 32, 256, 0, stream>>>(hist, offs, out4);
}